// Round 1
// baseline (67.357 us; speedup 1.0000x reference)
//
#include <hip/hip_runtime.h>

#define H 128
#define W 128
#define C 64
#define HW (H * W)
#define R 2
#define KD 5
#define KK 25
#define BX 16
#define BY 16
#define TW (BX + 2 * R)   // 20
#define TH (BY + 2 * R)   // 20
#define TPAD (TW + 1)     // 21 -> break bank-stride patterns
#define CB 8              // channels staged per barrier

__global__ __launch_bounds__(256)
void bam_corr_softmax_kernel(const float* __restrict__ f0,
                             const float* __restrict__ f1,
                             const float* __restrict__ f2,
                             float* __restrict__ out)
{
    __shared__ float tile[CB][TH][TPAD];

    const int tx = threadIdx.x;            // 0..15
    const int ty = threadIdx.y;            // 0..15
    const int tid = ty * BX + tx;

    const int tileX = blockIdx.x;          // 0..7
    const int tileY = blockIdx.y;          // 0..7
    const int img = blockIdx.z;            // 0..7 : img = v*2 + b
    const int v = img >> 1;
    const int b = img & 1;

    // variant -> (A, B) feature pair: corr = <A[:,p], B[:,p+off]>
    const float* A;
    const float* Bf;
    if (v == 0)      { A = f0; Bf = f2; }
    else if (v == 1) { A = f1; Bf = f2; }
    else if (v == 2) { A = f2; Bf = f0; }
    else             { A = f2; Bf = f1; }

    const int x0 = tileX * BX;
    const int y0 = tileY * BY;
    const int x = x0 + tx;
    const int y = y0 + ty;

    const float* Abase = A + (size_t)b * C * HW + (size_t)y * W + x;
    const float* Bbase = Bf + (size_t)b * C * HW;

    float corr[KK];
#pragma unroll
    for (int k = 0; k < KK; ++k) corr[k] = 0.f;

    for (int c0 = 0; c0 < C; c0 += CB) {
        // stage CB channel planes (20x20 halo tiles) of B into LDS
        for (int i = tid; i < CB * TH * TW; i += BX * BY) {
            int cc  = i / (TH * TW);
            int rem = i % (TH * TW);
            int ly  = rem / TW;
            int lx  = rem % TW;
            int gy  = y0 - R + ly;
            int gx  = x0 - R + lx;
            float val = 0.f;
            if (gy >= 0 && gy < H && gx >= 0 && gx < W)
                val = Bbase[(size_t)(c0 + cc) * HW + gy * W + gx];
            tile[cc][ly][lx] = val;
        }
        __syncthreads();

#pragma unroll
        for (int cc = 0; cc < CB; ++cc) {
            float a = Abase[(size_t)(c0 + cc) * HW];
#pragma unroll
            for (int ky = 0; ky < KD; ++ky)
#pragma unroll
                for (int kx = 0; kx < KD; ++kx)
                    corr[ky * KD + kx] =
                        fmaf(a, tile[cc][ty + ky][tx + kx], corr[ky * KD + kx]);
        }
        __syncthreads();
    }

    // masked softmax over the 25 taps + expected-offset reduction
    const float scale = 0.125f;   // 1/sqrt(64)
    float m = -1e30f;
#pragma unroll
    for (int ky = 0; ky < KD; ++ky) {
        int sy = y + ky - R;
#pragma unroll
        for (int kx = 0; kx < KD; ++kx) {
            int sx = x + kx - R;
            int k = ky * KD + kx;
            float cv = corr[k] * scale;
            bool valid = (sx >= 0) && (sx < W) && (sy >= 0) && (sy < H);
            cv = valid ? cv : -1e9f;
            corr[k] = cv;
            m = fmaxf(m, cv);
        }
    }

    float sum = 0.f, ox = 0.f, oy = 0.f;
#pragma unroll
    for (int ky = 0; ky < KD; ++ky) {
#pragma unroll
        for (int kx = 0; kx < KD; ++kx) {
            int k = ky * KD + kx;
            float e = __expf(corr[k] - m);
            sum += e;
            ox += e * (float)(kx - R);
            oy += e * (float)(ky - R);
        }
    }
    float inv = 1.f / sum;
    ox *= inv;
    oy *= inv;

    // out layout: [v][b][comp][y][x], img = v*2+b
    size_t outBase = ((size_t)img * 2) * HW + (size_t)y * W + x;
    out[outBase] = ox;
    out[outBase + HW] = oy;
}

extern "C" void kernel_launch(void* const* d_in, const int* in_sizes, int n_in,
                              void* d_out, int out_size, void* d_ws, size_t ws_size,
                              hipStream_t stream)
{
    const float* f0 = (const float*)d_in[0];
    const float* f1 = (const float*)d_in[1];
    const float* f2 = (const float*)d_in[2];
    float* out = (float*)d_out;

    dim3 block(BX, BY, 1);
    dim3 grid(W / BX, H / BY, 8);   // 8x8 tiles x (4 variants * 2 batches)
    bam_corr_softmax_kernel<<<grid, block, 0, stream>>>(f0, f1, f2, out);
}

// Round 2
// 59.921 us; speedup vs baseline: 1.1241x; 1.1241x over previous
//
#include <hip/hip_runtime.h>

#define H 128
#define W 128
#define C 64
#define HW (H * W)
#define R 2
#define KD 5
#define KK 25

#define TS 8              // 8x8 pixel tile per block
#define HS (TS + 2 * R)   // 12x12 halo
#define ROWP 16           // padded LDS row stride (floats)
#define PLANE (HS * ROWP) // 192 floats per channel plane
#define CBPER 4           // channels staged per group per round
#define NGROUP 4
#define GSTRIDE (CBPER * PLANE + 8) // 776 floats: group offset ≡ 8 (mod 32) banks
#define ROUNDS 4                    // 16 channels/group / CBPER
#define LDSF (NGROUP * GSTRIDE)     // 3104 floats = 12.4 KB

__global__ __launch_bounds__(256, 8)
void bam_corr_softmax_kernel(const float* __restrict__ f0,
                             const float* __restrict__ f1,
                             const float* __restrict__ f2,
                             float* __restrict__ out)
{
    __shared__ float lds[LDSF];

    const int tid  = threadIdx.x;
    const int lane = tid & 63;
    const int wav  = tid >> 6;     // 0..3
    const int pxl  = lane & 15;    // pixel-in-wave
    const int cs   = lane >> 4;    // 0..3 channel group
    const int px   = wav * 16 + pxl;  // 0..63 pixel in tile
    const int pyl  = px >> 3;      // local y 0..7
    const int pxx  = px & 7;       // local x 0..7

    const int tileX = blockIdx.x;
    const int tileY = blockIdx.y;
    const int img   = blockIdx.z;  // v*2 + b
    const int v = img >> 1;
    const int b = img & 1;

    const float* A;
    const float* Bf;
    if (v == 0)      { A = f0; Bf = f2; }
    else if (v == 1) { A = f1; Bf = f2; }
    else if (v == 2) { A = f2; Bf = f0; }
    else             { A = f2; Bf = f1; }

    const int x0 = tileX * TS;
    const int y0 = tileY * TS;
    const int x = x0 + pxx;
    const int y = y0 + pyl;

    const float* Abase = A + (size_t)b * C * HW + (size_t)y * W + x;
    const float* Bbase = Bf + (size_t)b * C * HW;

    float corr[KK];
#pragma unroll
    for (int k = 0; k < KK; ++k) corr[k] = 0.f;

    for (int r = 0; r < ROUNDS; ++r) {
        // stage 16 channel planes (CBPER per group) of the 12x12 halo
#pragma unroll
        for (int t = 0; t < 9; ++t) {
            int i   = tid + t * 256;        // 0..2303 = 16*144
            int p   = i / (HS * HS);        // plane 0..15
            int rem = i - p * (HS * HS);
            int ly  = rem / HS;
            int lx  = rem - ly * HS;
            int g   = p >> 2;
            int c   = p & 3;
            int ch  = g * 16 + r * CBPER + c;
            int gy  = y0 - R + ly;
            int gx  = x0 - R + lx;
            float val = 0.f;
            if (gy >= 0 && gy < H && gx >= 0 && gx < W)
                val = Bbase[(size_t)ch * HW + gy * W + gx];
            lds[g * GSTRIDE + c * PLANE + ly * ROWP + lx] = val;
        }
        __syncthreads();

        const float* lp0 = lds + cs * GSTRIDE + pyl * ROWP + pxx;
#pragma unroll
        for (int c = 0; c < CBPER; ++c) {
            float a = Abase[(size_t)(cs * 16 + r * CBPER + c) * HW];
            const float* lp = lp0 + c * PLANE;
#pragma unroll
            for (int ky = 0; ky < KD; ++ky)
#pragma unroll
                for (int kx = 0; kx < KD; ++kx)
                    corr[ky * KD + kx] =
                        fmaf(a, lp[ky * ROWP + kx], corr[ky * KD + kx]);
        }
        __syncthreads();
    }

    // reduce the 4 channel-group partials (lanes differ in bits 4,5)
#pragma unroll
    for (int k = 0; k < KK; ++k) {
        corr[k] += __shfl_xor(corr[k], 16, 64);
        corr[k] += __shfl_xor(corr[k], 32, 64);
    }

    // masked softmax + expected offset (all lanes compute, cs==0 stores)
    const float scale = 0.125f; // 1/sqrt(64)
    float m = -1e30f;
#pragma unroll
    for (int ky = 0; ky < KD; ++ky) {
        int sy = y + ky - R;
#pragma unroll
        for (int kx = 0; kx < KD; ++kx) {
            int sx = x + kx - R;
            int k = ky * KD + kx;
            float cv = corr[k] * scale;
            bool valid = (sx >= 0) && (sx < W) && (sy >= 0) && (sy < H);
            cv = valid ? cv : -1e9f;
            corr[k] = cv;
            m = fmaxf(m, cv);
        }
    }

    float sum = 0.f, ox = 0.f, oy = 0.f;
#pragma unroll
    for (int ky = 0; ky < KD; ++ky) {
#pragma unroll
        for (int kx = 0; kx < KD; ++kx) {
            int k = ky * KD + kx;
            float e = __expf(corr[k] - m);
            sum += e;
            ox += e * (float)(kx - R);
            oy += e * (float)(ky - R);
        }
    }
    float inv = 1.f / sum;
    ox *= inv;
    oy *= inv;

    if (cs == 0) {
        size_t outBase = ((size_t)img * 2) * HW + (size_t)y * W + x;
        out[outBase] = ox;
        out[outBase + HW] = oy;
    }
}

extern "C" void kernel_launch(void* const* d_in, const int* in_sizes, int n_in,
                              void* d_out, int out_size, void* d_ws, size_t ws_size,
                              hipStream_t stream)
{
    const float* f0 = (const float*)d_in[0];
    const float* f1 = (const float*)d_in[1];
    const float* f2 = (const float*)d_in[2];
    float* out = (float*)d_out;

    dim3 block(256, 1, 1);
    dim3 grid(W / TS, H / TS, 8); // 16x16 tiles x (4 variants * 2 batches)
    bam_corr_softmax_kernel<<<grid, block, 0, stream>>>(f0, f1, f2, out);
}

// Round 3
// 46.442 us; speedup vs baseline: 1.4503x; 1.2902x over previous
//
#include <hip/hip_runtime.h>

#define H 128
#define W 128
#define C 64
#define HW (H * W)
#define R 2
#define KD 5
#define KK 25

#define TS 8              // 8x8 pixel tile per block
#define HS (TS + 2 * R)   // 12x12 halo
#define ROWP 16           // padded LDS row stride (floats)
#define PLANE (HS * ROWP) // 192 floats per channel plane
#define CBPER 4           // channels staged per group per round
#define NGROUP 4
#define GSTRIDE (CBPER * PLANE + 8) // 776 floats: group offset ≡ 8 (mod 32) banks
#define ROUNDS 4                    // 16 channels/group / CBPER
#define LDSF (NGROUP * GSTRIDE)     // 3104 floats = 12.4 KB

#define NXCD 8

__global__ __launch_bounds__(256, 8)
void bam_corr_softmax_kernel(const float* __restrict__ f0,
                             const float* __restrict__ f1,
                             const float* __restrict__ f2,
                             float* __restrict__ out)
{
    __shared__ float lds[LDSF];

    const int tid  = threadIdx.x;
    const int lane = tid & 63;
    const int wav  = tid >> 6;     // 0..3
    const int pxl  = lane & 15;    // pixel-in-wave
    const int cs   = lane >> 4;    // 0..3 channel group
    const int px   = wav * 16 + pxl;  // 0..63 pixel in tile
    const int pyl  = px >> 3;      // local y 0..7
    const int pxx  = px & 7;       // local x 0..7

    // --- XCD-band decode: blockIdx.x % 8 = y-band -> same XCD L2 holds
    // all 3 features x 2 batches for its 16-row band (~3.1 MB < 4 MB L2).
    // Within a band, consecutive blocks on one XCD cycle the 8 (v,b) jobs
    // of the SAME tile (L1/L2-hot re-reads).
    const int i    = blockIdx.x;
    const int band = i & (NXCD - 1);       // 0..7 -> XCD (round-robin)
    const int j    = i >> 3;               // 0..255
    const int img  = j & 7;                // v*2 + b
    const int t    = j >> 3;               // 0..31 tiles in band
    const int tileX = t & 15;              // 0..15
    const int tileY = band * 2 + (t >> 4); // 0..15

    const int v = img >> 1;
    const int b = img & 1;

    const float* A;
    const float* Bf;
    if (v == 0)      { A = f0; Bf = f2; }
    else if (v == 1) { A = f1; Bf = f2; }
    else if (v == 2) { A = f2; Bf = f0; }
    else             { A = f2; Bf = f1; }

    const int x0 = tileX * TS;
    const int y0 = tileY * TS;
    const int x = x0 + pxx;
    const int y = y0 + pyl;

    const float* Abase = A + (size_t)b * C * HW + (size_t)y * W + x;
    const float* Bbase = Bf + (size_t)b * C * HW;

    float corr[KK];
#pragma unroll
    for (int k = 0; k < KK; ++k) corr[k] = 0.f;

    for (int r = 0; r < ROUNDS; ++r) {
        // stage 16 channel planes (CBPER per group) of the 12x12 halo
#pragma unroll
        for (int tt = 0; tt < 9; ++tt) {
            int ii  = tid + tt * 256;       // 0..2303 = 16*144
            int p   = ii / (HS * HS);       // plane 0..15
            int rem = ii - p * (HS * HS);
            int ly  = rem / HS;
            int lx  = rem - ly * HS;
            int g   = p >> 2;
            int c   = p & 3;
            int ch  = g * 16 + r * CBPER + c;
            int gy  = y0 - R + ly;
            int gx  = x0 - R + lx;
            float val = 0.f;
            if (gy >= 0 && gy < H && gx >= 0 && gx < W)
                val = Bbase[(size_t)ch * HW + gy * W + gx];
            lds[g * GSTRIDE + c * PLANE + ly * ROWP + lx] = val;
        }
        __syncthreads();

        const float* lp0 = lds + cs * GSTRIDE + pyl * ROWP + pxx;
#pragma unroll
        for (int c = 0; c < CBPER; ++c) {
            float a = Abase[(size_t)(cs * 16 + r * CBPER + c) * HW];
            const float* lp = lp0 + c * PLANE;
#pragma unroll
            for (int ky = 0; ky < KD; ++ky)
#pragma unroll
                for (int kx = 0; kx < KD; ++kx)
                    corr[ky * KD + kx] =
                        fmaf(a, lp[ky * ROWP + kx], corr[ky * KD + kx]);
        }
        __syncthreads();
    }

    // reduce the 4 channel-group partials (lanes differ in bits 4,5)
#pragma unroll
    for (int k = 0; k < KK; ++k) {
        corr[k] += __shfl_xor(corr[k], 16, 64);
        corr[k] += __shfl_xor(corr[k], 32, 64);
    }

    // masked softmax + expected offset (all lanes compute, cs==0 stores)
    const float scale = 0.125f; // 1/sqrt(64)
    float m = -1e30f;
#pragma unroll
    for (int ky = 0; ky < KD; ++ky) {
        int sy = y + ky - R;
#pragma unroll
        for (int kx = 0; kx < KD; ++kx) {
            int sx = x + kx - R;
            int k = ky * KD + kx;
            float cv = corr[k] * scale;
            bool valid = (sx >= 0) && (sx < W) && (sy >= 0) && (sy < H);
            cv = valid ? cv : -1e9f;
            corr[k] = cv;
            m = fmaxf(m, cv);
        }
    }

    float sum = 0.f, ox = 0.f, oy = 0.f;
#pragma unroll
    for (int ky = 0; ky < KD; ++ky) {
#pragma unroll
        for (int kx = 0; kx < KD; ++kx) {
            int k = ky * KD + kx;
            float e = __expf(corr[k] - m);
            sum += e;
            ox += e * (float)(kx - R);
            oy += e * (float)(ky - R);
        }
    }
    float inv = 1.f / sum;
    ox *= inv;
    oy *= inv;

    if (cs == 0) {
        size_t outBase = ((size_t)img * 2) * HW + (size_t)y * W + x;
        out[outBase] = ox;
        out[outBase + HW] = oy;
    }
}

extern "C" void kernel_launch(void* const* d_in, const int* in_sizes, int n_in,
                              void* d_out, int out_size, void* d_ws, size_t ws_size,
                              hipStream_t stream)
{
    const float* f0 = (const float*)d_in[0];
    const float* f1 = (const float*)d_in[1];
    const float* f2 = (const float*)d_in[2];
    float* out = (float*)d_out;

    dim3 block(256, 1, 1);
    dim3 grid(2048, 1, 1); // 8 bands x (8 img x 32 tiles)
    bam_corr_softmax_kernel<<<grid, block, 0, stream>>>(f0, f1, f2, out);
}

// Round 4
// 28.502 us; speedup vs baseline: 2.3633x; 1.6295x over previous
//
#include <hip/hip_runtime.h>

#define H 128
#define W 128
#define C 64
#define HW (H * W)
#define RAD 2
#define KD 5
#define KK 25

#define TSX 16            // output tile 16 wide
#define TSY 8             // x 8 tall
#define HX 20             // halo cols
#define HY 12             // halo rows
#define RSTR 20           // LDS row stride (floats)
#define PLANE 244         // padded plane stride: cs-groups alias banks only 2-way
#define CB 16             // channels staged per round
#define ROUNDS 4
#define LDSF (CB * PLANE) // 3904 floats = 15.6 KB

// cs-group reduction on the VALU pipe (gfx950 permlane swaps), no LDS traffic.
// permlane16_swap(a,a): a'=[r0,r0,r2,r2], b'=[r1,r1,r3,r3] -> a'+b' = xor16 sum
// permlane32_swap likewise for the 32-lane halves.
__device__ inline float cs_reduce(float x)
{
    float a = x, b = x;
    asm("v_permlane16_swap_b32 %0, %1" : "+v"(a), "+v"(b));
    float s = a + b;
    float c = s, d = s;
    asm("v_permlane32_swap_b32 %0, %1" : "+v"(c), "+v"(d));
    return c + d;
}

__global__ __launch_bounds__(256, 4)
void bam_corr_softmax_kernel(const float* __restrict__ f0,
                             const float* __restrict__ f1,
                             const float* __restrict__ f2,
                             float* __restrict__ out)
{
    __shared__ float lds[LDSF];

    const int tid  = threadIdx.x;
    const int lane = tid & 63;
    const int wav  = tid >> 6;
    const int cs   = lane >> 4;   // channel group 0..3
    const int s    = lane & 15;
    const int sy   = s >> 2;      // 0..3
    const int sxp  = s & 3;       // 0..3 (x-pair)
    const int wx   = wav & 1;
    const int wy   = wav >> 1;
    const int lx   = wx * 8 + sxp * 2;  // local x of first output (even)
    const int ly   = wy * 4 + sy;       // local y

    // XCD banding: blockIdx.x % 8 = 16-row y-band -> one XCD's L2 holds the
    // band's working set (~3.1 MB). Consecutive blocks cycle the 8 (v,b)
    // jobs of the same tile.
    const int i    = blockIdx.x;
    const int band = i & 7;
    const int j    = i >> 3;
    const int img  = j & 7;       // v*2 + b
    const int t    = j >> 3;      // 0..15
    const int tileX = t & 7;
    const int tileY = band * 2 + (t >> 3);

    const int v = img >> 1;
    const int b = img & 1;

    const float* A;
    const float* Bf;
    if (v == 0)      { A = f0; Bf = f2; }
    else if (v == 1) { A = f1; Bf = f2; }
    else if (v == 2) { A = f2; Bf = f0; }
    else             { A = f2; Bf = f1; }

    const int x0 = tileX * TSX;
    const int y0 = tileY * TSY;
    const int x  = x0 + lx;       // first output x (even)
    const int y  = y0 + ly;

    const float* Abase = A + (size_t)b * C * HW + (size_t)y * W + x;
    const float* Bbase = Bf + (size_t)b * C * HW;

    float c0[KK], c1[KK];
#pragma unroll
    for (int k = 0; k < KK; ++k) { c0[k] = 0.f; c1[k] = 0.f; }

    for (int r = 0; r < ROUNDS; ++r) {
        // ---- stage CB channel planes (12x20 halo) as float4 chunks ----
#pragma unroll
        for (int it = 0; it < 4; ++it) {
            int q = tid + it * 256;
            if (q < CB * HY * 5) {              // 960 chunks
                int p   = q / 60;               // plane 0..15
                int rem = q - p * 60;
                int row = rem / 5;
                int c4  = rem - row * 5;
                int ch  = r * CB + p;
                int gy  = y0 - RAD + row;
                int gx  = x0 - RAD + c4 * 4;
                float4 val;
                if (gy >= 0 && gy < H && gx >= 0 && gx + 3 < W) {
                    val = *reinterpret_cast<const float4*>(
                        Bbase + (size_t)ch * HW + gy * W + gx);
                } else {
                    float vv[4];
#pragma unroll
                    for (int e = 0; e < 4; ++e) {
                        int gxe = gx + e;
                        vv[e] = (gy >= 0 && gy < H && gxe >= 0 && gxe < W)
                              ? Bbase[(size_t)ch * HW + (size_t)gy * W + gxe]
                              : 0.f;
                    }
                    val = make_float4(vv[0], vv[1], vv[2], vv[3]);
                }
                *reinterpret_cast<float4*>(&lds[p * PLANE + row * RSTR + c4 * 4]) = val;
            }
        }
        __syncthreads();

        // ---- compute: 4 channels per cs-group, 2 x-outputs per thread ----
#pragma unroll
        for (int c = 0; c < 4; ++c) {
            const int pl = cs * 4 + c;
            const int ch = r * CB + pl;
            float2 a2 = *reinterpret_cast<const float2*>(Abase + (size_t)ch * HW);
            const float* bp = &lds[pl * PLANE + ly * RSTR + lx];
#pragma unroll
            for (int ky = 0; ky < KD; ++ky) {
                const float* rp = bp + ky * RSTR;
                float2 w01 = *reinterpret_cast<const float2*>(rp);
                float2 w23 = *reinterpret_cast<const float2*>(rp + 2);
                float2 w45 = *reinterpret_cast<const float2*>(rp + 4);
                const int kb = ky * KD;
                c0[kb + 0] = fmaf(a2.x, w01.x, c0[kb + 0]);
                c0[kb + 1] = fmaf(a2.x, w01.y, c0[kb + 1]);
                c0[kb + 2] = fmaf(a2.x, w23.x, c0[kb + 2]);
                c0[kb + 3] = fmaf(a2.x, w23.y, c0[kb + 3]);
                c0[kb + 4] = fmaf(a2.x, w45.x, c0[kb + 4]);
                c1[kb + 0] = fmaf(a2.y, w01.y, c1[kb + 0]);
                c1[kb + 1] = fmaf(a2.y, w23.x, c1[kb + 1]);
                c1[kb + 2] = fmaf(a2.y, w23.y, c1[kb + 2]);
                c1[kb + 3] = fmaf(a2.y, w45.x, c1[kb + 3]);
                c1[kb + 4] = fmaf(a2.y, w45.y, c1[kb + 4]);
            }
        }
        __syncthreads();
    }

    // ---- reduce the 4 channel-group partials (VALU permlane swaps) ----
#pragma unroll
    for (int k = 0; k < KK; ++k) {
        c0[k] = cs_reduce(c0[k]);
        c1[k] = cs_reduce(c1[k]);
    }

    // ---- masked softmax + expected offset for both outputs ----
    const float scale = 0.125f; // 1/sqrt(64)
    float ox0, oy0, ox1, oy1;
    {
        float m = -1e30f;
#pragma unroll
        for (int ky = 0; ky < KD; ++ky) {
            int syy = y + ky - RAD;
#pragma unroll
            for (int kx = 0; kx < KD; ++kx) {
                int sxx = x + kx - RAD;
                int k = ky * KD + kx;
                float cv = c0[k] * scale;
                bool valid = (sxx >= 0) && (sxx < W) && (syy >= 0) && (syy < H);
                cv = valid ? cv : -1e9f;
                c0[k] = cv;
                m = fmaxf(m, cv);
            }
        }
        float sum = 0.f, ox = 0.f, oy = 0.f;
#pragma unroll
        for (int ky = 0; ky < KD; ++ky)
#pragma unroll
            for (int kx = 0; kx < KD; ++kx) {
                int k = ky * KD + kx;
                float e = __expf(c0[k] - m);
                sum += e;
                ox += e * (float)(kx - RAD);
                oy += e * (float)(ky - RAD);
            }
        float inv = 1.f / sum;
        ox0 = ox * inv; oy0 = oy * inv;
    }
    {
        const int x1c = x + 1;
        float m = -1e30f;
#pragma unroll
        for (int ky = 0; ky < KD; ++ky) {
            int syy = y + ky - RAD;
#pragma unroll
            for (int kx = 0; kx < KD; ++kx) {
                int sxx = x1c + kx - RAD;
                int k = ky * KD + kx;
                float cv = c1[k] * scale;
                bool valid = (sxx >= 0) && (sxx < W) && (syy >= 0) && (syy < H);
                cv = valid ? cv : -1e9f;
                c1[k] = cv;
                m = fmaxf(m, cv);
            }
        }
        float sum = 0.f, ox = 0.f, oy = 0.f;
#pragma unroll
        for (int ky = 0; ky < KD; ++ky)
#pragma unroll
            for (int kx = 0; kx < KD; ++kx) {
                int k = ky * KD + kx;
                float e = __expf(c1[k] - m);
                sum += e;
                ox += e * (float)(kx - RAD);
                oy += e * (float)(ky - RAD);
            }
        float inv = 1.f / sum;
        ox1 = ox * inv; oy1 = oy * inv;
    }

    if (cs == 0) {
        size_t ob = ((size_t)img * 2) * HW + (size_t)y * W + x;
        *reinterpret_cast<float2*>(&out[ob])      = make_float2(ox0, ox1);
        *reinterpret_cast<float2*>(&out[ob + HW]) = make_float2(oy0, oy1);
    }
}

extern "C" void kernel_launch(void* const* d_in, const int* in_sizes, int n_in,
                              void* d_out, int out_size, void* d_ws, size_t ws_size,
                              hipStream_t stream)
{
    const float* f0 = (const float*)d_in[0];
    const float* f1 = (const float*)d_in[1];
    const float* f2 = (const float*)d_in[2];
    float* out = (float*)d_out;

    dim3 block(256, 1, 1);
    dim3 grid(1024, 1, 1); // 8 bands x (8 img x 16 tiles of 16x8)
    bam_corr_softmax_kernel<<<grid, block, 0, stream>>>(f0, f1, f2, out);
}